// Round 10
// baseline (690.305 us; speedup 1.0000x reference)
//
#include <hip/hip_runtime.h>
#include <math.h>

#define NPER  4096
#define NTOT  16384
#define EPER  49152
#define ETOT  196608
#define FD    128
#define F3    384
#define KR    20
#define PI_F  3.14159265358979f

typedef unsigned short u16;
typedef __attribute__((ext_vector_type(8))) short s16x8;
typedef __attribute__((ext_vector_type(4))) float f32x4;
typedef _Float16 h16x2 __attribute__((ext_vector_type(2)));
typedef _Float16 h16x4 __attribute__((ext_vector_type(4)));
typedef _Float16 h16x8 __attribute__((ext_vector_type(8)));

#if defined(__has_builtin)
#if __has_builtin(__builtin_amdgcn_fdot2)
#define FDOT2(a,b,c) __builtin_amdgcn_fdot2((a),(b),(c),false)
#endif
#endif
#ifndef FDOT2
#define FDOT2(a,b,c) ((float)(a)[0]*(float)(b)[0] + (float)(a)[1]*(float)(b)[1] + (c))
#endif

__device__ __forceinline__ float silu_f(float x){ return x / (1.0f + __expf(-x)); }
__device__ __forceinline__ u16 f2b(float x){
    unsigned u = __float_as_uint(x);
    u = u + 0x7FFFu + ((u >> 16) & 1u);
    return (u16)(u >> 16);
}
__device__ __forceinline__ float b2f(u16 h){ return __uint_as_float(((unsigned)h) << 16); }

// 64B edge record: {dirn.xyz, cut} + 20 f16 of es*cut (RBF pre-scaled by cutoff)
struct __align__(16) EdgeRec {
    float4 ed;
    h16x8  es0;   // pairs 0-3
    h16x8  es1;   // pairs 4-7
    h16x4  es2;   // pairs 8-9
    h16x4  pad;
};

// ---------------- pass 1: recv counts only ----------------
__global__ __launch_bounds__(256) void ecount_kernel(
    const int* __restrict__ aedges, int* __restrict__ counts)
{
    int e = blockIdx.x * blockDim.x + threadIdx.x;
    if (e >= ETOT) return;
    int r = aedges[(size_t)e*2+1] + (e / EPER)*NPER;
    atomicAdd(&counts[r],1);
}

// ---------------- exclusive scan counts -> row_off ----------------
__global__ __launch_bounds__(1024) void scan_kernel(const int* __restrict__ counts,
                                                    int* __restrict__ row_off)
{
    __shared__ int sdata[1024];
    int t = threadIdx.x;
    int base = t * 16;
    int local[16];
    int s = 0;
    #pragma unroll
    for (int i=0;i<16;++i){ local[i]=s; s += counts[base+i]; }
    sdata[t] = s;
    __syncthreads();
    for (int off=1; off<1024; off<<=1) {
        int val = (t>=off) ? sdata[t-off] : 0;
        __syncthreads();
        sdata[t] += val;
        __syncthreads();
    }
    int chunk_off = (t==0) ? 0 : sdata[t-1];
    #pragma unroll
    for (int i=0;i<16;++i) row_off[base+i] = chunk_off + local[i];
    if (t==1023) row_off[NTOT] = sdata[1023];
}

// ---------------- pass 2: compute EdgeRec + scatter directly into CSR ----------------
__global__ __launch_bounds__(256) void fill_kernel(
    const float* __restrict__ xyz, const float* __restrict__ cell,
    const int* __restrict__ aedges, const float* __restrict__ edisp,
    const int* __restrict__ row_off, int* __restrict__ cursor,
    int* __restrict__ sd_csr, EdgeRec* __restrict__ erec_csr)
{
    int e = blockIdx.x * blockDim.x + threadIdx.x;
    if (e >= ETOT) return;
    int b = e / EPER;
    int s = aedges[(size_t)e*2+0] + b*NPER;
    int r = aedges[(size_t)e*2+1] + b*NPER;
    const float* cb = cell + b*9;
    float c0 = edisp[(size_t)e*3+0], c1 = edisp[(size_t)e*3+1], c2 = edisp[(size_t)e*3+2];
    float diff[3];
    #pragma unroll
    for (int d=0; d<3; ++d) {
        float disp = c0*cb[d] + c1*cb[3+d] + c2*cb[6+d];
        diff[d] = xyz[(size_t)r*3+d] - (xyz[(size_t)s*3+d] + disp);
    }
    float dist = sqrtf(diff[0]*diff[0]+diff[1]*diff[1]+diff[2]*diff[2]);
    float cut = (dist < 5.0f) ? 0.5f*(__cosf(PI_F*dist*0.2f)+1.0f) : 0.0f;
    float invg = 1.0f/fmaxf(dist,1e-12f);
    EdgeRec rec;
    rec.ed = make_float4(diff[0]*invg, diff[1]*invg, diff[2]*invg, cut);
    float theta = dist*(PI_F*0.2f);
    float s1 = __sinf(theta), cth = __cosf(theta);
    float scale = cut / dist;
    float twoc = 2.f*cth;
    float sm1 = 0.f, sk = s1;
    _Float16 esv[20];
    #pragma unroll
    for (int k=0;k<20;++k){
        esv[k] = (_Float16)(sk*scale);
        float nx = twoc*sk - sm1;
        sm1 = sk; sk = nx;
    }
    union { h16x8 v; _Float16 h[8]; } u0, u1;
    union { h16x4 v; _Float16 h[4]; } u2;
    #pragma unroll
    for (int i=0;i<8;++i){ u0.h[i]=esv[i]; u1.h[i]=esv[8+i]; }
    #pragma unroll
    for (int i=0;i<4;++i) u2.h[i]=esv[16+i];
    rec.es0=u0.v; rec.es1=u1.v; rec.es2=u2.v;
    rec.pad = (h16x4)((_Float16)0);
    int slot = atomicAdd(&cursor[r], 1);
    int pos = row_off[r] + slot;
    sd_csr[pos] = s;
    erec_csr[pos] = rec;
}

// ---------------- weight fp32 -> bf16 conversion ----------------
// U_W/V_W are re-packed per layer: w_UV + l*32768 = [U_l rows (16384) | V_l rows (16384)]
__global__ __launch_bounds__(256) void wconv_kernel(
    const float* __restrict__ w0, const float* __restrict__ w1,
    const float* __restrict__ w2, const float* __restrict__ w3,
    const float* __restrict__ w4, const float* __restrict__ w5,
    const float* __restrict__ w6, const float* __restrict__ w7,
    u16* __restrict__ dst)
{
    int t = blockIdx.x*256 + threadIdx.x;
    if (t >= 589824) return;
    const float* src; int off; int d = t;
    if      (t < 32768)  { src=w0; off=t; }
    else if (t < 49152)  { src=w1; off=t-32768; }
    else if (t < 98304)  { src=w2; off=t-49152; }
    else if (t < 245760) { src=w3; off=t-98304; }
    else if (t < 294912) { int o=t-245760; int l=o>>14; int r=o&16383; src=w4; off=o;
                           d = 245760 + l*32768 + r; }
    else if (t < 344064) { int o=t-294912; int l=o>>14; int r=o&16383; src=w5; off=o;
                           d = 245760 + l*32768 + 16384 + r; }
    else if (t < 442368) { src=w6; off=t-344064; }
    else                 { src=w7; off=t-442368; }
    dst[d] = f2b(src[off]);
}

// ---------------- filter weights fp32 -> f16 ----------------
__global__ __launch_bounds__(256) void wfilt_kernel(const float* __restrict__ fW,
                                                    _Float16* __restrict__ dst)
{
    int t = blockIdx.x*256 + threadIdx.x;
    if (t < 3*F3*KR) dst[t] = (_Float16)fW[t];
}

// ---------------- h = [atom_emb[nodes], V*potW + potb] -> bf16 ----------------
__global__ __launch_bounds__(256) void hbuild_kernel(const int* __restrict__ nodes,
    const float* __restrict__ atom_emb, const float* __restrict__ V_flat,
    const float* __restrict__ pot_W, const float* __restrict__ pot_b,
    u16* __restrict__ h)
{
    int t = blockIdx.x * blockDim.x + threadIdx.x;   // NTOT*256
    int n = t >> 8, k = t & 255;
    float val;
    if (k < FD) val = atom_emb[(size_t)nodes[n]*FD + k];
    else { int f = k - FD; val = V_flat[n]*pot_W[f] + pot_b[f]; }
    h[t] = f2b(val);
}

// ---------------- v0 = E_flat[:,c] * vec_w[f] (fp32 + vq quad) ----------------
__global__ __launch_bounds__(256) void v0_kernel(const float* __restrict__ E_flat,
    const float* __restrict__ vec_w, float* __restrict__ v0, u16* __restrict__ vq)
{
    int t = blockIdx.x * blockDim.x + threadIdx.x;   // NTOT*384
    int n = t / F3, r = t - n*F3;
    int c = r >> 7, f = r & 127;
    float val = E_flat[(size_t)n*3 + c] * vec_w[f];
    v0[t] = val;
    vq[((size_t)n*FD + f)*4 + c] = f2b(val);
}

// ---------------- bf16 MFMA GEMM (init path only) ----------------
template<int ACT>
__global__ __launch_bounds__(256) void bgemm_kernel(
    const u16* __restrict__ A, int lda,
    const u16* __restrict__ W, int Kdim,
    const float* __restrict__ bias,
    float* __restrict__ C, int ldc,
    u16* __restrict__ Cb, int ldcb,
    u16* __restrict__ Cq, int qoff)
{
    const int tid  = threadIdx.x;
    const int wave = tid >> 6, lane = tid & 63;
    const int q = lane >> 4, im = lane & 15;
    const int row0 = blockIdx.y*64 + wave*16;
    const int col0 = blockIdx.x*64;
    f32x4 acc[4];
    #pragma unroll
    for (int n=0;n<4;++n) acc[n] = (f32x4){0.f,0.f,0.f,0.f};
    const u16* Ap = A + (size_t)(row0+im)*lda + q*8;
    const u16* Wp = W + (size_t)(col0+im)*Kdim + q*8;
    for (int k0 = 0; k0 < Kdim; k0 += 32) {
        s16x8 af = *(const s16x8*)(Ap + k0);
        #pragma unroll
        for (int n=0;n<4;++n) {
            s16x8 bf = *(const s16x8*)(Wp + (size_t)n*16*Kdim + k0);
            acc[n] = __builtin_amdgcn_mfma_f32_16x16x32_bf16(af, bf, acc[n], 0, 0, 0);
        }
    }
    #pragma unroll
    for (int n=0;n<4;++n) {
        int col = col0 + n*16 + im;
        float bv = bias ? bias[col] : 0.f;
        #pragma unroll
        for (int r=0;r<4;++r) {
            int row = row0 + q*4 + r;
            float v = acc[n][r] + bv;
            if (ACT) v = silu_f(v);
            if (C)  C[(size_t)row*ldc + col] = v;
            if (Cb) Cb[(size_t)row*ldcb + col] = f2b(v);
            if (Cq) Cq[((size_t)row*FD + (col & 127))*4 + (col >> 7) + qoff] = f2b(v);
        }
    }
}

// LDS swizzles (guide G4): XOR row bits into the 16B-slot bits of the byte addr.
#define HID_OFF(row, col2b) ((unsigned)((row)*256 + (col2b)*2) ^ ((unsigned)((row)&7) << 4))
#define M_OFF(row, col2b)   ((unsigned)((row)*512 + (col2b)*2) ^ ((unsigned)((row)&7) << 4))
// 2-way XOR for fp32 [16][128] rows: separates write-rows (low bits vary) AND
// read-rows (bit-2 varies) into 2 bank-halves; 2-way conflicts are free (G4).
#define DK(row) (((((unsigned)(row))&1u)^((((unsigned)(row))>>2)&1u))<<6)

// ---------------- fused msg MLP (R8 shape, proven) ----------------
__global__ __launch_bounds__(256) void msgmlp_kernel(
    const u16* __restrict__ A,      // s_bf (NTOT x 128)
    const u16* __restrict__ W1,     // msg1 layer (128 x 128)
    const float* __restrict__ b1,   // (128)
    const u16* __restrict__ W2,     // msg2 layer (384 x 128)
    const float* __restrict__ b2,   // (384)
    u16* __restrict__ sq)           // quads, writes slots 0..2
{
    __shared__ u16 hid[16*FD];
    const int tid = threadIdx.x;
    const int wave = tid >> 6, lane = tid & 63;
    const int q = lane >> 4, im = lane & 15;
    const int row0 = blockIdx.x * 16;
    // ---- stage 1 ----
    {
        f32x4 acc[2];
        #pragma unroll
        for (int n=0;n<2;++n) acc[n] = (f32x4){0.f,0.f,0.f,0.f};
        const u16* Ap = A + (size_t)(row0+im)*FD + q*8;
        #pragma unroll
        for (int k0=0;k0<FD;k0+=32) {
            s16x8 af = *(const s16x8*)(Ap + k0);
            #pragma unroll
            for (int n=0;n<2;++n) {
                s16x8 bf = *(const s16x8*)(W1 + (size_t)(wave*32+n*16+im)*FD + k0 + q*8);
                acc[n] = __builtin_amdgcn_mfma_f32_16x16x32_bf16(af, bf, acc[n], 0, 0, 0);
            }
        }
        #pragma unroll
        for (int n=0;n<2;++n) {
            int col = wave*32 + n*16 + im;
            float bv = b1[col];
            #pragma unroll
            for (int r=0;r<4;++r) {
                int row = q*4 + r;
                *(u16*)((char*)hid + HID_OFF(row, col)) = f2b(silu_f(acc[n][r]+bv));
            }
        }
    }
    __syncthreads();
    // ---- stage 2 ----
    s16x8 af[4];
    #pragma unroll
    for (int k=0;k<4;++k)
        af[k] = *(const s16x8*)((char*)hid + HID_OFF(im, k*32+q*8));
    #pragma unroll
    for (int jj=0;jj<2;++jj) {
        int j = wave*2 + jj;
        f32x4 a2[3];
        #pragma unroll
        for (int g=0;g<3;++g) a2[g] = (f32x4){0.f,0.f,0.f,0.f};
        #pragma unroll
        for (int k=0;k<4;++k) {
            #pragma unroll
            for (int g=0;g<3;++g) {
                s16x8 bf = *(const s16x8*)(W2 + (size_t)(g*128 + j*16 + im)*FD + k*32 + q*8);
                a2[g] = __builtin_amdgcn_mfma_f32_16x16x32_bf16(af[k], bf, a2[g], 0, 0, 0);
            }
        }
        int fcol = j*16 + im;
        float c0 = b2[fcol], c1 = b2[FD+fcol], c2 = b2[2*FD+fcol];
        #pragma unroll
        for (int r=0;r<4;++r) {
            int row = row0 + q*4 + r;
            size_t t4 = ((size_t)row*FD + fcol)*4;
            unsigned pk = (unsigned)f2b(a2[0][r]+c0) | ((unsigned)f2b(a2[1][r]+c1) << 16);
            *(unsigned*)(sq + t4) = pk;       // slots 0,1 (8B-aligned)
            sq[t4+2] = f2b(a2[2][r]+c2);      // slot 2
        }
    }
}

// ---------------- fused UV GEMM + Vn/dot + upd MLP + epilogue ----------------
// v3: LDS 45->40 KB so 4 blocks/CU (was 3): hid overlays dead mL (extra barrier
// between stage-1 mL reads and overlay writes); dotL/uvL zero-padded [*,128]
// with 2-way DK XOR (free per G4) instead of PADF padding.
__global__ __launch_bounds__(256) void upduv_kernel(
    const u16* __restrict__ vmid4,   // vmid4_bf (4*NTOT x 128)
    const u16* __restrict__ Wuv,     // (256 x 128): rows 0-127 U, 128-255 V
    const u16* __restrict__ W1,      // upd1 layer (128 x 256)
    const float* __restrict__ b1,    // (128)
    const u16* __restrict__ W2,      // upd2 layer (384 x 128)
    const float* __restrict__ b2,    // (384)
    const float* __restrict__ s_mid, const float* __restrict__ v_mid,
    float* __restrict__ outp, u16* __restrict__ s_bf,
    u16* __restrict__ sq, u16* __restrict__ vq)
{
    __shared__ u16   mL[16*256];       // 8 KB; low 4 KB reused as hid after stage 1
    __shared__ float dotL[16*128];     // 8 KB  (DK swizzle)
    __shared__ float uvL[3*16*128];    // 24 KB [c][node][f] (DK swizzle on node)
    const int tid = threadIdx.x;
    const int wave = tid >> 6, lane = tid & 63;
    const int q = lane >> 4, im = lane & 15;
    const int node0 = blockIdx.x * 16;

    // ---- phase A: UV GEMM + lane-local reductions -> LDS ----
    {
        const int prow0 = blockIdx.x*64 + wave*16;   // padded-row space
        const u16* Ap = vmid4 + (size_t)(prow0+im)*FD + q*8;
        s16x8 af[4];
        #pragma unroll
        for (int k=0;k<4;++k) af[k] = *(const s16x8*)(Ap + k*32);
        const int nloc = wave*4 + q;
        #pragma unroll
        for (int j=0;j<8;++j) {
            f32x4 aU = (f32x4){0.f,0.f,0.f,0.f};
            f32x4 aV = (f32x4){0.f,0.f,0.f,0.f};
            const u16* WpU = Wuv + (size_t)(j*16+im)*FD + q*8;
            const u16* WpV = WpU + (size_t)128*FD;
            #pragma unroll
            for (int k=0;k<4;++k) {
                s16x8 bU = *(const s16x8*)(WpU + k*32);
                s16x8 bV = *(const s16x8*)(WpV + k*32);
                aU = __builtin_amdgcn_mfma_f32_16x16x32_bf16(af[k], bU, aU, 0, 0, 0);
                aV = __builtin_amdgcn_mfma_f32_16x16x32_bf16(af[k], bV, aV, 0, 0, 0);
            }
            int fcol = j*16 + im;
            float u0=aU[0], u1=aU[1], u2=aU[2];
            float w0=aV[0], w1=aV[1], w2=aV[2];
            *(float*)((char*)dotL + (((unsigned)(nloc*512 + fcol*4)) ^ DK(nloc))) =
                u0*w0 + u1*w1 + u2*w2;
            *(u16*)((char*)mL + M_OFF(nloc, 128+fcol)) = f2b(sqrtf(w0*w0+w1*w1+w2*w2));
            *(float*)((char*)uvL + (((unsigned)(0*8192 + nloc*512 + fcol*4)) ^ DK(nloc))) = u0;
            *(float*)((char*)uvL + (((unsigned)(1*8192 + nloc*512 + fcol*4)) ^ DK(nloc))) = u1;
            *(float*)((char*)uvL + (((unsigned)(2*8192 + nloc*512 + fcol*4)) ^ DK(nloc))) = u2;
        }
    }
    // ---- m tile s-half (cooperative, 8 bf16 per thread, one 16B LDS store) ----
    {
        int row = tid >> 4;
        int c0  = (tid & 15) * 8;
        const float* sp = s_mid + (size_t)(node0+row)*FD + c0;
        union { s16x8 v; u16 h[8]; } pk;
        #pragma unroll
        for (int i=0;i<8;++i) pk.h[i] = f2b(sp[i]);
        *(s16x8*)((char*)mL + M_OFF(row, c0)) = pk.v;
    }
    __syncthreads();
    // ---- stage 1: m @ W1 (K=256) -> acc (mL still live) ----
    f32x4 acc1[2];
    #pragma unroll
    for (int n=0;n<2;++n) acc1[n] = (f32x4){0.f,0.f,0.f,0.f};
    #pragma unroll
    for (int k0=0;k0<256;k0+=32) {
        s16x8 af = *(const s16x8*)((char*)mL + M_OFF(im, k0+q*8));
        #pragma unroll
        for (int n=0;n<2;++n) {
            s16x8 bf = *(const s16x8*)(W1 + (size_t)(wave*32+n*16+im)*256 + k0 + q*8);
            acc1[n] = __builtin_amdgcn_mfma_f32_16x16x32_bf16(af, bf, acc1[n], 0, 0, 0);
        }
    }
    __syncthreads();           // all waves done READING mL before hid overlays it
    u16* hid = mL;             // overlay: mL dead from here on
    #pragma unroll
    for (int n=0;n<2;++n) {
        int col = wave*32 + n*16 + im;
        float bv = b1[col];
        #pragma unroll
        for (int r=0;r<4;++r) {
            int row = q*4 + r;
            *(u16*)((char*)hid + HID_OFF(row, col)) = f2b(silu_f(acc1[n][r]+bv));
        }
    }
    __syncthreads();
    // ---- stage 2 + epilogue (dot/Uv from LDS) ----
    s16x8 af2[4];
    #pragma unroll
    for (int k=0;k<4;++k)
        af2[k] = *(const s16x8*)((char*)hid + HID_OFF(im, k*32+q*8));
    #pragma unroll
    for (int jj=0;jj<2;++jj) {
        int j = wave*2 + jj;
        f32x4 a2[3];
        #pragma unroll
        for (int g=0;g<3;++g) a2[g] = (f32x4){0.f,0.f,0.f,0.f};
        #pragma unroll
        for (int k=0;k<4;++k) {
            #pragma unroll
            for (int g=0;g<3;++g) {
                s16x8 bf = *(const s16x8*)(W2 + (size_t)(g*128 + j*16 + im)*FD + k*32 + q*8);
                a2[g] = __builtin_amdgcn_mfma_f32_16x16x32_bf16(af2[k], bf, a2[g], 0, 0, 0);
            }
        }
        int fcol = j*16 + im;
        float b_ss = b2[fcol], b_sv = b2[FD+fcol], b_vv = b2[2*FD+fcol];
        #pragma unroll
        for (int r=0;r<4;++r) {
            int rl = q*4 + r;                 // node-local row
            int row = node0 + rl;
            float a_ss = a2[0][r] + b_ss;
            float a_sv = a2[1][r] + b_sv;
            float a_vv = a2[2][r] + b_vv;
            size_t t = (size_t)row*FD + fcol;
            float dotv = *(const float*)((char*)dotL +
                             (((unsigned)(rl*512 + fcol*4)) ^ DK(rl)));
            float sval = s_mid[t] + a_ss + a_sv*dotv;
            outp[(size_t)row*512 + fcol] = sval;
            s_bf[t] = f2b(sval);
            sq[t*4 + 3] = f2b(sval);
            ushort4 pack;
            #pragma unroll
            for (int c=0;c<3;++c) {
                size_t vi = ((size_t)row*3 + c)*FD + fcol;
                float uvv = *(const float*)((char*)uvL +
                               (((unsigned)(c*8192 + rl*512 + fcol*4)) ^ DK(rl)));
                float vval = v_mid[vi] + a_vv*uvv;
                outp[(size_t)row*512 + (1+c)*FD + fcol] = vval;
                ((u16*)&pack)[c] = f2b(vval);
            }
            ((u16*)&pack)[3] = 0;
            *(ushort4*)(vq + t*4) = pack;   // quad {v0,v1,v2,pad}: one 8B store
        }
    }
}

// ---------------- agg edge step ----------------
__device__ __forceinline__ void edge_step(
    const EdgeRec& er, ushort4 s4, ushort4 v4,
    const h16x2* wp,   // 30 pairs: [0..9]=row f, [10..19]=row 128+f, [20..29]=row 256+f
    float b0, float b1, float b2,
    float& acc_s, float& av0, float& av1, float& av2)
{
    union { h16x8 v; h16x2 p[4]; } e0, e1;
    union { h16x4 v; h16x2 p[2]; } e2;
    e0.v = er.es0; e1.v = er.es1; e2.v = er.es2;
    h16x2 ep[10] = {e0.p[0],e0.p[1],e0.p[2],e0.p[3],
                    e1.p[0],e1.p[1],e1.p[2],e1.p[3],
                    e2.p[0],e2.p[1]};
    float4 ed = er.ed;
    float d0=0.f, d1=0.f, d2=0.f;
    #pragma unroll
    for (int j=0;j<10;++j){
        d0 = FDOT2(ep[j], wp[j],    d0);
        d1 = FDOT2(ep[j], wp[10+j], d1);
        d2 = FDOT2(ep[j], wp[20+j], d2);
    }
    float g_sv = d0 + b0*ed.w;
    float g_ev = d1 + b1*ed.w;
    float g_ns = d2 + b2*ed.w;
    float fo_sv = g_sv * b2f(s4.x);
    float fo_ev = g_ev * b2f(s4.y);
    float fo_ns = g_ns * b2f(s4.z);
    acc_s += b2f(s4.w) * fo_ns;
    av0 += b2f(v4.x)*fo_sv + fo_ev*ed.x;
    av1 += b2f(v4.y)*fo_sv + fo_ev*ed.y;
    av2 += b2f(v4.z)*fo_sv + fo_ev*ed.z;
}

// ---------------- fused filter + gather aggregation (R1 structure, proven) ----------------
// v3: XCD-affinity block swizzle — default round-robin puts every batch's
// gather set (32 MB) on every XCD's 4 MB L2; remap so each XCD serves recv
// nodes of ONE batch (8 MB working set). Bijection over the 8192-block grid.
__global__ __launch_bounds__(256) __attribute__((amdgpu_waves_per_eu(4,8)))
void agg_kernel(
    const float* __restrict__ s_prev_f, int s_ldaf,
    const float* __restrict__ v_prev_f, int v_nstrf,
    const ushort4* __restrict__ sq, const ushort4* __restrict__ vq,
    const EdgeRec* __restrict__ erec_csr,
    const int* __restrict__ sd_csr, const int* __restrict__ row_off,
    const _Float16* __restrict__ wf, const float* __restrict__ fb,
    float* __restrict__ s_mid, float* __restrict__ v_mid,
    u16* __restrict__ vmid4_bf)
{
    const int f   = threadIdx.x & 127;
    const int sub = threadIdx.x >> 7;
    h16x2 wp[30];
    #pragma unroll
    for (int rsel=0; rsel<3; ++rsel){
        const h16x4* rp = (const h16x4*)(wf + (size_t)(rsel*FD + f)*KR);
        #pragma unroll
        for (int i=0;i<5;++i){
            union { h16x4 v; h16x2 p[2]; } t; t.v = rp[i];
            wp[rsel*10+2*i]   = t.p[0];
            wp[rsel*10+2*i+1] = t.p[1];
        }
    }
    const float b0 = fb[f], b1 = fb[FD+f], b2 = fb[2*FD+f];

    // XCD-affinity swizzle: xcd = b&7 (de-facto round-robin), pos = b>>3.
    // XCD pair (xcd>>1) serves batch (xcd>>1); grid = 8192 blocks exactly.
    const int bsw = blockIdx.x;
    const int nb  = ((bsw & 7) >> 1)*2048 + (bsw & 1)*1024 + (bsw >> 3);
    const int n = nb*2 + sub;
    const int beg = __builtin_amdgcn_readfirstlane(row_off[n]);
    const int end = __builtin_amdgcn_readfirstlane(row_off[n+1]);
    float acc_s=0.f, av0=0.f, av1=0.f, av2=0.f;

    // prologue: load pair 0 (guarded via clamped indices; index 0 is a safe dummy)
    int i0 = (beg   < end) ? beg   : 0;
    int i1 = (beg+1 < end) ? beg+1 : i0;
    int sd0 = __builtin_amdgcn_readfirstlane(sd_csr[i0]);
    int sd1 = __builtin_amdgcn_readfirstlane(sd_csr[i1]);
    ushort4 sA = sq[(size_t)sd0*FD + f];
    ushort4 vA = vq[(size_t)sd0*FD + f];
    ushort4 sB = sq[(size_t)sd1*FD + f];
    ushort4 vB = vq[(size_t)sd1*FD + f];
    EdgeRec r0 = erec_csr[i0];
    EdgeRec r1 = erec_csr[i1];

    for (int idx = beg; idx + 2 <= end; idx += 2) {
        // prefetch next pair while this pair computes
        int j0 = (idx+2 < end) ? idx+2 : 0;
        int j1 = (idx+3 < end) ? idx+3 : j0;
        int nsd0 = __builtin_amdgcn_readfirstlane(sd_csr[j0]);
        int nsd1 = __builtin_amdgcn_readfirstlane(sd_csr[j1]);
        ushort4 nsA = sq[(size_t)nsd0*FD + f];
        ushort4 nvA = vq[(size_t)nsd0*FD + f];
        ushort4 nsB = sq[(size_t)nsd1*FD + f];
        ushort4 nvB = vq[(size_t)nsd1*FD + f];
        EdgeRec nr0 = erec_csr[j0];
        EdgeRec nr1 = erec_csr[j1];

        edge_step(r0, sA, vA, wp, b0,b1,b2, acc_s, av0, av1, av2);
        edge_step(r1, sB, vB, wp, b0,b1,b2, acc_s, av0, av1, av2);

        sA=nsA; vA=nvA; sB=nsB; vB=nvB; r0=nr0; r1=nr1;
    }
    // tail: when degree is odd, the last edge's data has rotated into slot A
    if (((end - beg) & 1) && beg < end) {
        edge_step(r0, sA, vA, wp, b0,b1,b2, acc_s, av0, av1, av2);
    }

    float smv = s_prev_f[(size_t)n*s_ldaf+f] + acc_s;
    s_mid[(size_t)n*FD+f] = smv;
    const float* vp = v_prev_f + (size_t)n*v_nstrf;
    float o0 = vp[f]+av0, o1 = vp[FD+f]+av1, o2 = vp[2*FD+f]+av2;
    size_t vo = (size_t)n*F3;
    v_mid[vo+f]=o0;        v_mid[vo+FD+f]=o1;        v_mid[vo+2*FD+f]=o2;
    size_t v4 = (size_t)n*512;                // node-padded bf16 (row 4n+3 stays 0)
    vmid4_bf[v4+f]=f2b(o0); vmid4_bf[v4+FD+f]=f2b(o1); vmid4_bf[v4+2*FD+f]=f2b(o2);
}

extern "C" void kernel_launch(void* const* d_in, const int* in_sizes, int n_in,
                              void* d_out, int out_size, void* d_ws, size_t ws_size,
                              hipStream_t stream)
{
    (void)in_sizes; (void)n_in; (void)out_size; (void)ws_size;
    const float* atom_xyz = (const float*)d_in[0];
    const float* cell     = (const float*)d_in[1];
    const int*   nodes    = (const int*)d_in[2];
    const int*   aedges   = (const int*)d_in[3];
    const float* edisp    = (const float*)d_in[4];
    const float* V_flat   = (const float*)d_in[5];
    const float* E_flat   = (const float*)d_in[6];
    const float* atom_emb = (const float*)d_in[7];
    const float* pot_W    = (const float*)d_in[8];
    const float* pot_b    = (const float*)d_in[9];
    const float* init_W1  = (const float*)d_in[10];
    const float* init_b1  = (const float*)d_in[11];
    const float* init_W2  = (const float*)d_in[12];
    const float* init_b2  = (const float*)d_in[13];
    const float* vec_w    = (const float*)d_in[14];
    const float* filt_W   = (const float*)d_in[15];
    const float* filt_b   = (const float*)d_in[16];
    const float* msg_W1   = (const float*)d_in[17];
    const float* msg_b1   = (const float*)d_in[18];
    const float* msg_W2   = (const float*)d_in[19];
    const float* msg_b2   = (const float*)d_in[20];
    const float* U_W      = (const float*)d_in[21];
    const float* V_W      = (const float*)d_in[22];
    const float* upd_W1   = (const float*)d_in[23];
    const float* upd_b1   = (const float*)d_in[24];
    const float* upd_W2   = (const float*)d_in[25];
    const float* upd_b2   = (const float*)d_in[26];

    float* out = (float*)d_out;
    char* base = (char*)d_ws;
    size_t o = 0;
    auto alloc = [&](size_t bytes)->char* { char* r = base + o; o += (bytes + 255) & ~(size_t)255; return r; };

    float* s0     = (float*)alloc((size_t)NTOT*FD*4);
    float* v0     = (float*)alloc((size_t)NTOT*F3*4);
    float* s_mid  = (float*)alloc((size_t)NTOT*FD*4);
    float* v_mid  = (float*)alloc((size_t)NTOT*F3*4);
    EdgeRec* erec_csr = (EdgeRec*)alloc((size_t)ETOT*sizeof(EdgeRec));
    u16* h_bf     = (u16*)alloc((size_t)NTOT*256*2);    // init path
    u16* s_bf     = (u16*)alloc((size_t)NTOT*FD*2);
    u16* sq       = (u16*)alloc((size_t)NTOT*FD*4*2);   // quads {so0,so1,so2,s}
    u16* vq       = (u16*)alloc((size_t)NTOT*FD*4*2);   // quads {v0,v1,v2,pad}
    u16* hid_bf   = (u16*)alloc((size_t)NTOT*FD*2);     // init path only
    u16* vmid4_bf = (u16*)alloc((size_t)NTOT*4*FD*2);   // node-padded bf16 (row 4n+3 = 0)
    u16* wts      = (u16*)alloc((size_t)589824*2);
    _Float16* wf16 = (_Float16*)alloc((size_t)3*F3*KR*2);
    int* sd_csr   = (int*)alloc((size_t)ETOT*4);
    int* row_off  = (int*)alloc((size_t)(NTOT+1)*4);
    int* counts   = (int*)alloc((size_t)NTOT*4);
    int* cursor   = (int*)alloc((size_t)NTOT*4);

    hipMemsetAsync(counts, 0, NTOT*sizeof(int), stream);
    hipMemsetAsync(cursor, 0, NTOT*sizeof(int), stream);
    hipMemsetAsync(vmid4_bf, 0, (size_t)NTOT*4*FD*2, stream);  // pad rows stay 0 all layers

    ecount_kernel<<<ETOT/256, 256, 0, stream>>>(aedges, counts);
    scan_kernel<<<1, 1024, 0, stream>>>(counts, row_off);
    fill_kernel<<<ETOT/256, 256, 0, stream>>>(atom_xyz, cell, aedges, edisp,
        row_off, cursor, sd_csr, erec_csr);
    wconv_kernel<<<(589824+255)/256, 256, 0, stream>>>(
        init_W1, init_W2, msg_W1, msg_W2, U_W, V_W, upd_W1, upd_W2, wts);
    wfilt_kernel<<<(3*F3*KR+255)/256, 256, 0, stream>>>(filt_W, wf16);

    const u16* w_init1 = wts + 0;
    const u16* w_init2 = wts + 32768;
    const u16* w_msg1  = wts + 49152;    // 3 x 16384
    const u16* w_msg2  = wts + 98304;    // 3 x 49152
    const u16* w_UV    = wts + 245760;   // 3 x 32768: per layer [U rows | V rows]
    const u16* w_upd1  = wts + 344064;   // 3 x 32768
    const u16* w_upd2  = wts + 442368;   // 3 x 49152

    hbuild_kernel<<<NTOT*256/256, 256, 0, stream>>>(nodes, atom_emb, V_flat, pot_W, pot_b, h_bf);
    bgemm_kernel<1><<<dim3(FD/64, NTOT/64), 256, 0, stream>>>(
        h_bf, 256, w_init1, 256, init_b1, (float*)nullptr, 0, hid_bf, FD, (u16*)nullptr, 0);
    bgemm_kernel<0><<<dim3(FD/64, NTOT/64), 256, 0, stream>>>(
        hid_bf, FD, w_init2, FD, init_b2, s0, FD, s_bf, FD, sq, 3);
    v0_kernel<<<NTOT*F3/256, 256, 0, stream>>>(E_flat, vec_w, v0, vq);

    const float* s_prev_f = s0;  int s_ldaf  = FD;
    const float* v_prev_f = v0;  int v_nstrf = 3*FD;
    for (int l = 0; l < 3; ++l) {
        msgmlp_kernel<<<NTOT/16, 256, 0, stream>>>(
            s_bf, w_msg1 + (size_t)l*16384, msg_b1 + (size_t)l*FD,
            w_msg2 + (size_t)l*49152, msg_b2 + (size_t)l*F3, sq);
        agg_kernel<<<NTOT/2, 256, 0, stream>>>(s_prev_f, s_ldaf, v_prev_f, v_nstrf,
            (const ushort4*)sq, (const ushort4*)vq, erec_csr, sd_csr, row_off,
            wf16 + (size_t)l*F3*KR, filt_b + (size_t)l*F3, s_mid, v_mid, vmid4_bf);
        float* outp = out + (size_t)l*NTOT*512;
        upduv_kernel<<<NTOT/16, 256, 0, stream>>>(
            vmid4_bf, w_UV + (size_t)l*32768,
            w_upd1 + (size_t)l*32768, upd_b1 + (size_t)l*FD,
            w_upd2 + (size_t)l*49152, upd_b2 + (size_t)l*F3,
            s_mid, v_mid, outp, s_bf, sq, vq);
        s_prev_f = outp;        s_ldaf  = 512;
        v_prev_f = outp + FD;   v_nstrf = 512;
    }
}

// Round 11
// 645.715 us; speedup vs baseline: 1.0691x; 1.0691x over previous
//
#include <hip/hip_runtime.h>
#include <math.h>

#define NPER  4096
#define NTOT  16384
#define EPER  49152
#define ETOT  196608
#define FD    128
#define F3    384
#define KR    20
#define PI_F  3.14159265358979f
#define PADF  132

typedef unsigned short u16;
typedef __attribute__((ext_vector_type(8))) short s16x8;
typedef __attribute__((ext_vector_type(4))) float f32x4;
typedef _Float16 h16x2 __attribute__((ext_vector_type(2)));
typedef _Float16 h16x4 __attribute__((ext_vector_type(4)));
typedef _Float16 h16x8 __attribute__((ext_vector_type(8)));

#if defined(__has_builtin)
#if __has_builtin(__builtin_amdgcn_fdot2)
#define FDOT2(a,b,c) __builtin_amdgcn_fdot2((a),(b),(c),false)
#endif
#endif
#ifndef FDOT2
#define FDOT2(a,b,c) ((float)(a)[0]*(float)(b)[0] + (float)(a)[1]*(float)(b)[1] + (c))
#endif

__device__ __forceinline__ float silu_f(float x){ return x / (1.0f + __expf(-x)); }
__device__ __forceinline__ u16 f2b(float x){
    unsigned u = __float_as_uint(x);
    u = u + 0x7FFFu + ((u >> 16) & 1u);
    return (u16)(u >> 16);
}
__device__ __forceinline__ float b2f(u16 h){ return __uint_as_float(((unsigned)h) << 16); }

// 64B edge record: {dirn.xyz, cut} + 20 f16 of es*cut (RBF pre-scaled by cutoff)
struct __align__(16) EdgeRec {
    float4 ed;
    h16x8  es0;   // pairs 0-3
    h16x8  es1;   // pairs 4-7
    h16x4  es2;   // pairs 8-9
    h16x4  pad;
};

// ---------------- pass 1: recv counts only ----------------
__global__ __launch_bounds__(256) void ecount_kernel(
    const int* __restrict__ aedges, int* __restrict__ counts)
{
    int e = blockIdx.x * blockDim.x + threadIdx.x;
    if (e >= ETOT) return;
    int r = aedges[(size_t)e*2+1] + (e / EPER)*NPER;
    atomicAdd(&counts[r],1);
}

// ---------------- exclusive scan counts -> row_off ----------------
__global__ __launch_bounds__(1024) void scan_kernel(const int* __restrict__ counts,
                                                    int* __restrict__ row_off)
{
    __shared__ int sdata[1024];
    int t = threadIdx.x;
    int base = t * 16;
    int local[16];
    int s = 0;
    #pragma unroll
    for (int i=0;i<16;++i){ local[i]=s; s += counts[base+i]; }
    sdata[t] = s;
    __syncthreads();
    for (int off=1; off<1024; off<<=1) {
        int val = (t>=off) ? sdata[t-off] : 0;
        __syncthreads();
        sdata[t] += val;
        __syncthreads();
    }
    int chunk_off = (t==0) ? 0 : sdata[t-1];
    #pragma unroll
    for (int i=0;i<16;++i) row_off[base+i] = chunk_off + local[i];
    if (t==1023) row_off[NTOT] = sdata[1023];
}

// ---------------- pass 2: compute EdgeRec + scatter directly into CSR ----------------
__global__ __launch_bounds__(256) void fill_kernel(
    const float* __restrict__ xyz, const float* __restrict__ cell,
    const int* __restrict__ aedges, const float* __restrict__ edisp,
    const int* __restrict__ row_off, int* __restrict__ cursor,
    int* __restrict__ sd_csr, EdgeRec* __restrict__ erec_csr)
{
    int e = blockIdx.x * blockDim.x + threadIdx.x;
    if (e >= ETOT) return;
    int b = e / EPER;
    int s = aedges[(size_t)e*2+0] + b*NPER;
    int r = aedges[(size_t)e*2+1] + b*NPER;
    const float* cb = cell + b*9;
    float c0 = edisp[(size_t)e*3+0], c1 = edisp[(size_t)e*3+1], c2 = edisp[(size_t)e*3+2];
    float diff[3];
    #pragma unroll
    for (int d=0; d<3; ++d) {
        float disp = c0*cb[d] + c1*cb[3+d] + c2*cb[6+d];
        diff[d] = xyz[(size_t)r*3+d] - (xyz[(size_t)s*3+d] + disp);
    }
    float dist = sqrtf(diff[0]*diff[0]+diff[1]*diff[1]+diff[2]*diff[2]);
    float cut = (dist < 5.0f) ? 0.5f*(__cosf(PI_F*dist*0.2f)+1.0f) : 0.0f;
    float invg = 1.0f/fmaxf(dist,1e-12f);
    EdgeRec rec;
    rec.ed = make_float4(diff[0]*invg, diff[1]*invg, diff[2]*invg, cut);
    float theta = dist*(PI_F*0.2f);
    float s1 = __sinf(theta), cth = __cosf(theta);
    float scale = cut / dist;
    float twoc = 2.f*cth;
    float sm1 = 0.f, sk = s1;
    _Float16 esv[20];
    #pragma unroll
    for (int k=0;k<20;++k){
        esv[k] = (_Float16)(sk*scale);
        float nx = twoc*sk - sm1;
        sm1 = sk; sk = nx;
    }
    union { h16x8 v; _Float16 h[8]; } u0, u1;
    union { h16x4 v; _Float16 h[4]; } u2;
    #pragma unroll
    for (int i=0;i<8;++i){ u0.h[i]=esv[i]; u1.h[i]=esv[8+i]; }
    #pragma unroll
    for (int i=0;i<4;++i) u2.h[i]=esv[16+i];
    rec.es0=u0.v; rec.es1=u1.v; rec.es2=u2.v;
    rec.pad = (h16x4)((_Float16)0);
    int slot = atomicAdd(&cursor[r], 1);
    int pos = row_off[r] + slot;
    sd_csr[pos] = s;
    erec_csr[pos] = rec;
}

// ---------------- weight fp32 -> bf16 conversion ----------------
// U_W/V_W are re-packed per layer: w_UV + l*32768 = [U_l rows (16384) | V_l rows (16384)]
__global__ __launch_bounds__(256) void wconv_kernel(
    const float* __restrict__ w0, const float* __restrict__ w1,
    const float* __restrict__ w2, const float* __restrict__ w3,
    const float* __restrict__ w4, const float* __restrict__ w5,
    const float* __restrict__ w6, const float* __restrict__ w7,
    u16* __restrict__ dst)
{
    int t = blockIdx.x*256 + threadIdx.x;
    if (t >= 589824) return;
    const float* src; int off; int d = t;
    if      (t < 32768)  { src=w0; off=t; }
    else if (t < 49152)  { src=w1; off=t-32768; }
    else if (t < 98304)  { src=w2; off=t-49152; }
    else if (t < 245760) { src=w3; off=t-98304; }
    else if (t < 294912) { int o=t-245760; int l=o>>14; int r=o&16383; src=w4; off=o;
                           d = 245760 + l*32768 + r; }
    else if (t < 344064) { int o=t-294912; int l=o>>14; int r=o&16383; src=w5; off=o;
                           d = 245760 + l*32768 + 16384 + r; }
    else if (t < 442368) { src=w6; off=t-344064; }
    else                 { src=w7; off=t-442368; }
    dst[d] = f2b(src[off]);
}

// ---------------- filter weights fp32 -> f16 ----------------
__global__ __launch_bounds__(256) void wfilt_kernel(const float* __restrict__ fW,
                                                    _Float16* __restrict__ dst)
{
    int t = blockIdx.x*256 + threadIdx.x;
    if (t < 3*F3*KR) dst[t] = (_Float16)fW[t];
}

// ---------------- v0: vq quad slots only (v0 array eliminated; agg l=0 recomputes) ----------------
__global__ __launch_bounds__(256) void v0_kernel(const float* __restrict__ E_flat,
    const float* __restrict__ vec_w, u16* __restrict__ vq)
{
    int t = blockIdx.x * blockDim.x + threadIdx.x;   // NTOT*384
    int n = t / F3, r = t - n*F3;
    int c = r >> 7, f = r & 127;
    vq[((size_t)n*FD + f)*4 + c] = f2b(E_flat[(size_t)n*3 + c] * vec_w[f]);
}

// LDS swizzles (guide G4): XOR row bits into the 16B-slot bits of the byte addr.
#define HID_OFF(row, col2b) ((unsigned)((row)*256 + (col2b)*2) ^ ((unsigned)((row)&7) << 4))
#define M_OFF(row, col2b)   ((unsigned)((row)*512 + (col2b)*2) ^ ((unsigned)((row)&7) << 4))

// ---------------- fused init: h=[emb,pot] (LDS) -> silu(h@W1+b1) -> @W2+b2 ----------------
// Replaces hbuild + 2 init bgemms. Stage-1/2 are the proven updmlp/msgmlp stages.
__global__ __launch_bounds__(256) void hinit_kernel(
    const int* __restrict__ nodes,
    const float* __restrict__ atom_emb, const float* __restrict__ V_flat,
    const float* __restrict__ pot_W, const float* __restrict__ pot_b,
    const u16* __restrict__ W1,     // init_W1 (128 x 256)
    const float* __restrict__ b1,   // (128)
    const u16* __restrict__ W2,     // init_W2 (128 x 128)
    const float* __restrict__ b2,   // (128)
    float* __restrict__ s0, u16* __restrict__ s_bf, u16* __restrict__ sq)
{
    __shared__ u16 mL[16*256];
    __shared__ u16 hid[16*FD];
    const int tid = threadIdx.x;
    const int wave = tid >> 6, lane = tid & 63;
    const int q = lane >> 4, im = lane & 15;
    const int row0 = blockIdx.x * 16;
    // ---- stage 0: build h tile in LDS ----
    {
        int row = tid >> 4;
        int c0  = (tid & 15) * 16;
        int nid = nodes[row0 + row];
        float vf = V_flat[row0 + row];
        #pragma unroll
        for (int i=0;i<16;++i) {
            int col = c0 + i;
            float val = (col < FD) ? atom_emb[(size_t)nid*FD + col]
                                   : vf * pot_W[col-FD] + pot_b[col-FD];
            *(u16*)((char*)mL + M_OFF(row, col)) = f2b(val);
        }
    }
    __syncthreads();
    // ---- stage 1: h @ W1 (K=256) -> silu -> hid ----
    {
        f32x4 acc[2];
        #pragma unroll
        for (int n=0;n<2;++n) acc[n] = (f32x4){0.f,0.f,0.f,0.f};
        #pragma unroll
        for (int k0=0;k0<256;k0+=32) {
            s16x8 af = *(const s16x8*)((char*)mL + M_OFF(im, k0+q*8));
            #pragma unroll
            for (int n=0;n<2;++n) {
                s16x8 bf = *(const s16x8*)(W1 + (size_t)(wave*32+n*16+im)*256 + k0 + q*8);
                acc[n] = __builtin_amdgcn_mfma_f32_16x16x32_bf16(af, bf, acc[n], 0, 0, 0);
            }
        }
        #pragma unroll
        for (int n=0;n<2;++n) {
            int col = wave*32 + n*16 + im;
            float bv = b1[col];
            #pragma unroll
            for (int r=0;r<4;++r) {
                int row = q*4 + r;
                *(u16*)((char*)hid + HID_OFF(row, col)) = f2b(silu_f(acc[n][r]+bv));
            }
        }
    }
    __syncthreads();
    // ---- stage 2: hid @ W2 (N=128) -> s0, s_bf, sq slot 3 ----
    s16x8 af2[4];
    #pragma unroll
    for (int k=0;k<4;++k)
        af2[k] = *(const s16x8*)((char*)hid + HID_OFF(im, k*32+q*8));
    #pragma unroll
    for (int jj=0;jj<2;++jj) {
        int j = wave*2 + jj;
        f32x4 a2 = (f32x4){0.f,0.f,0.f,0.f};
        #pragma unroll
        for (int k=0;k<4;++k) {
            s16x8 bf = *(const s16x8*)(W2 + (size_t)(j*16 + im)*FD + k*32 + q*8);
            a2 = __builtin_amdgcn_mfma_f32_16x16x32_bf16(af2[k], bf, a2, 0, 0, 0);
        }
        int fcol = j*16 + im;
        float bv = b2[fcol];
        #pragma unroll
        for (int r=0;r<4;++r) {
            int row = row0 + q*4 + r;
            float v = a2[r] + bv;
            size_t t = (size_t)row*FD + fcol;
            s0[t] = v;
            s_bf[t] = f2b(v);
            sq[t*4 + 3] = f2b(v);
        }
    }
}

// ---------------- fused msg MLP (R8 shape, proven) ----------------
__global__ __launch_bounds__(256) void msgmlp_kernel(
    const u16* __restrict__ A,      // s_bf (NTOT x 128)
    const u16* __restrict__ W1,     // msg1 layer (128 x 128)
    const float* __restrict__ b1,   // (128)
    const u16* __restrict__ W2,     // msg2 layer (384 x 128)
    const float* __restrict__ b2,   // (384)
    u16* __restrict__ sq)           // quads, writes slots 0..2
{
    __shared__ u16 hid[16*FD];
    const int tid = threadIdx.x;
    const int wave = tid >> 6, lane = tid & 63;
    const int q = lane >> 4, im = lane & 15;
    const int row0 = blockIdx.x * 16;
    // ---- stage 1 ----
    {
        f32x4 acc[2];
        #pragma unroll
        for (int n=0;n<2;++n) acc[n] = (f32x4){0.f,0.f,0.f,0.f};
        const u16* Ap = A + (size_t)(row0+im)*FD + q*8;
        #pragma unroll
        for (int k0=0;k0<FD;k0+=32) {
            s16x8 af = *(const s16x8*)(Ap + k0);
            #pragma unroll
            for (int n=0;n<2;++n) {
                s16x8 bf = *(const s16x8*)(W1 + (size_t)(wave*32+n*16+im)*FD + k0 + q*8);
                acc[n] = __builtin_amdgcn_mfma_f32_16x16x32_bf16(af, bf, acc[n], 0, 0, 0);
            }
        }
        #pragma unroll
        for (int n=0;n<2;++n) {
            int col = wave*32 + n*16 + im;
            float bv = b1[col];
            #pragma unroll
            for (int r=0;r<4;++r) {
                int row = q*4 + r;
                *(u16*)((char*)hid + HID_OFF(row, col)) = f2b(silu_f(acc[n][r]+bv));
            }
        }
    }
    __syncthreads();
    // ---- stage 2 ----
    s16x8 af[4];
    #pragma unroll
    for (int k=0;k<4;++k)
        af[k] = *(const s16x8*)((char*)hid + HID_OFF(im, k*32+q*8));
    #pragma unroll
    for (int jj=0;jj<2;++jj) {
        int j = wave*2 + jj;
        f32x4 a2[3];
        #pragma unroll
        for (int g=0;g<3;++g) a2[g] = (f32x4){0.f,0.f,0.f,0.f};
        #pragma unroll
        for (int k=0;k<4;++k) {
            #pragma unroll
            for (int g=0;g<3;++g) {
                s16x8 bf = *(const s16x8*)(W2 + (size_t)(g*128 + j*16 + im)*FD + k*32 + q*8);
                a2[g] = __builtin_amdgcn_mfma_f32_16x16x32_bf16(af[k], bf, a2[g], 0, 0, 0);
            }
        }
        int fcol = j*16 + im;
        float c0 = b2[fcol], c1 = b2[FD+fcol], c2 = b2[2*FD+fcol];
        #pragma unroll
        for (int r=0;r<4;++r) {
            int row = row0 + q*4 + r;
            size_t t4 = ((size_t)row*FD + fcol)*4;
            unsigned pk = (unsigned)f2b(a2[0][r]+c0) | ((unsigned)f2b(a2[1][r]+c1) << 16);
            *(unsigned*)(sq + t4) = pk;       // slots 0,1 (8B-aligned)
            sq[t4+2] = f2b(a2[2][r]+c2);      // slot 2
        }
    }
}

// ---------------- fused UV GEMM + Vn/dot + upd MLP + epilogue (R9 exact) ----------------
__global__ __launch_bounds__(256) void upduv_kernel(
    const u16* __restrict__ vmid4,   // vmid4_bf (4*NTOT x 128)
    const u16* __restrict__ Wuv,     // (256 x 128): rows 0-127 U, 128-255 V
    const u16* __restrict__ W1,      // upd1 layer (128 x 256)
    const float* __restrict__ b1,    // (128)
    const u16* __restrict__ W2,      // upd2 layer (384 x 128)
    const float* __restrict__ b2,    // (384)
    const float* __restrict__ s_mid, const float* __restrict__ v_mid,
    float* __restrict__ outp, u16* __restrict__ s_bf,
    u16* __restrict__ sq, u16* __restrict__ vq)
{
    __shared__ u16   mL[16*256];       // 8 KB  (M_OFF swizzle)
    __shared__ float dotL[16*PADF];    // 8.25 KB
    __shared__ float uvL[48*PADF];     // 24.75 KB  [(node*3+c)*PADF + f]
    __shared__ u16   hid[16*FD];       // 4 KB  (HID_OFF swizzle)
    const int tid = threadIdx.x;
    const int wave = tid >> 6, lane = tid & 63;
    const int q = lane >> 4, im = lane & 15;
    const int node0 = blockIdx.x * 16;

    // ---- phase A: UV GEMM + lane-local reductions -> LDS ----
    {
        const int prow0 = blockIdx.x*64 + wave*16;   // padded-row space
        const u16* Ap = vmid4 + (size_t)(prow0+im)*FD + q*8;
        s16x8 af[4];
        #pragma unroll
        for (int k=0;k<4;++k) af[k] = *(const s16x8*)(Ap + k*32);
        const int nloc = wave*4 + q;
        #pragma unroll
        for (int j=0;j<8;++j) {
            f32x4 aU = (f32x4){0.f,0.f,0.f,0.f};
            f32x4 aV = (f32x4){0.f,0.f,0.f,0.f};
            const u16* WpU = Wuv + (size_t)(j*16+im)*FD + q*8;
            const u16* WpV = WpU + (size_t)128*FD;
            #pragma unroll
            for (int k=0;k<4;++k) {
                s16x8 bU = *(const s16x8*)(WpU + k*32);
                s16x8 bV = *(const s16x8*)(WpV + k*32);
                aU = __builtin_amdgcn_mfma_f32_16x16x32_bf16(af[k], bU, aU, 0, 0, 0);
                aV = __builtin_amdgcn_mfma_f32_16x16x32_bf16(af[k], bV, aV, 0, 0, 0);
            }
            int fcol = j*16 + im;
            float u0=aU[0], u1=aU[1], u2=aU[2];
            float w0=aV[0], w1=aV[1], w2=aV[2];
            dotL[nloc*PADF + fcol] = u0*w0 + u1*w1 + u2*w2;
            *(u16*)((char*)mL + M_OFF(nloc, 128+fcol)) = f2b(sqrtf(w0*w0+w1*w1+w2*w2));
            uvL[(nloc*3+0)*PADF + fcol] = u0;
            uvL[(nloc*3+1)*PADF + fcol] = u1;
            uvL[(nloc*3+2)*PADF + fcol] = u2;
        }
    }
    // ---- m tile s-half (cooperative, 8 bf16 per thread, one 16B LDS store) ----
    {
        int row = tid >> 4;
        int c0  = (tid & 15) * 8;
        const float* sp = s_mid + (size_t)(node0+row)*FD + c0;
        union { s16x8 v; u16 h[8]; } pk;
        #pragma unroll
        for (int i=0;i<8;++i) pk.h[i] = f2b(sp[i]);
        *(s16x8*)((char*)mL + M_OFF(row, c0)) = pk.v;
    }
    __syncthreads();
    // ---- stage 1: m @ W1 (K=256) -> hid ----
    {
        f32x4 acc[2];
        #pragma unroll
        for (int n=0;n<2;++n) acc[n] = (f32x4){0.f,0.f,0.f,0.f};
        #pragma unroll
        for (int k0=0;k0<256;k0+=32) {
            s16x8 af = *(const s16x8*)((char*)mL + M_OFF(im, k0+q*8));
            #pragma unroll
            for (int n=0;n<2;++n) {
                s16x8 bf = *(const s16x8*)(W1 + (size_t)(wave*32+n*16+im)*256 + k0 + q*8);
                acc[n] = __builtin_amdgcn_mfma_f32_16x16x32_bf16(af, bf, acc[n], 0, 0, 0);
            }
        }
        #pragma unroll
        for (int n=0;n<2;++n) {
            int col = wave*32 + n*16 + im;
            float bv = b1[col];
            #pragma unroll
            for (int r=0;r<4;++r) {
                int row = q*4 + r;
                *(u16*)((char*)hid + HID_OFF(row, col)) = f2b(silu_f(acc[n][r]+bv));
            }
        }
    }
    __syncthreads();
    // ---- stage 2 + epilogue (dot/Uv from LDS) ----
    s16x8 af2[4];
    #pragma unroll
    for (int k=0;k<4;++k)
        af2[k] = *(const s16x8*)((char*)hid + HID_OFF(im, k*32+q*8));
    #pragma unroll
    for (int jj=0;jj<2;++jj) {
        int j = wave*2 + jj;
        f32x4 a2[3];
        #pragma unroll
        for (int g=0;g<3;++g) a2[g] = (f32x4){0.f,0.f,0.f,0.f};
        #pragma unroll
        for (int k=0;k<4;++k) {
            #pragma unroll
            for (int g=0;g<3;++g) {
                s16x8 bf = *(const s16x8*)(W2 + (size_t)(g*128 + j*16 + im)*FD + k*32 + q*8);
                a2[g] = __builtin_amdgcn_mfma_f32_16x16x32_bf16(af2[k], bf, a2[g], 0, 0, 0);
            }
        }
        int fcol = j*16 + im;
        float b_ss = b2[fcol], b_sv = b2[FD+fcol], b_vv = b2[2*FD+fcol];
        #pragma unroll
        for (int r=0;r<4;++r) {
            int rl = q*4 + r;                 // node-local row
            int row = node0 + rl;
            float a_ss = a2[0][r] + b_ss;
            float a_sv = a2[1][r] + b_sv;
            float a_vv = a2[2][r] + b_vv;
            size_t t = (size_t)row*FD + fcol;
            float sval = s_mid[t] + a_ss + a_sv*dotL[rl*PADF + fcol];
            outp[(size_t)row*512 + fcol] = sval;
            s_bf[t] = f2b(sval);
            sq[t*4 + 3] = f2b(sval);
            ushort4 pack;
            #pragma unroll
            for (int c=0;c<3;++c) {
                size_t vi = ((size_t)row*3 + c)*FD + fcol;
                float vval = v_mid[vi] + a_vv*uvL[(rl*3+c)*PADF + fcol];
                outp[(size_t)row*512 + (1+c)*FD + fcol] = vval;
                ((u16*)&pack)[c] = f2b(vval);
            }
            ((u16*)&pack)[3] = 0;
            *(ushort4*)(vq + t*4) = pack;   // quad {v0,v1,v2,pad}: one 8B store
        }
    }
}

// ---------------- agg edge step ----------------
__device__ __forceinline__ void edge_step(
    const EdgeRec& er, ushort4 s4, ushort4 v4,
    const h16x2* wp,   // 30 pairs: [0..9]=row f, [10..19]=row 128+f, [20..29]=row 256+f
    float b0, float b1, float b2,
    float& acc_s, float& av0, float& av1, float& av2)
{
    union { h16x8 v; h16x2 p[4]; } e0, e1;
    union { h16x4 v; h16x2 p[2]; } e2;
    e0.v = er.es0; e1.v = er.es1; e2.v = er.es2;
    h16x2 ep[10] = {e0.p[0],e0.p[1],e0.p[2],e0.p[3],
                    e1.p[0],e1.p[1],e1.p[2],e1.p[3],
                    e2.p[0],e2.p[1]};
    float4 ed = er.ed;
    float d0=0.f, d1=0.f, d2=0.f;
    #pragma unroll
    for (int j=0;j<10;++j){
        d0 = FDOT2(ep[j], wp[j],    d0);
        d1 = FDOT2(ep[j], wp[10+j], d1);
        d2 = FDOT2(ep[j], wp[20+j], d2);
    }
    float g_sv = d0 + b0*ed.w;
    float g_ev = d1 + b1*ed.w;
    float g_ns = d2 + b2*ed.w;
    float fo_sv = g_sv * b2f(s4.x);
    float fo_ev = g_ev * b2f(s4.y);
    float fo_ns = g_ns * b2f(s4.z);
    acc_s += b2f(s4.w) * fo_ns;
    av0 += b2f(v4.x)*fo_sv + fo_ev*ed.x;
    av1 += b2f(v4.y)*fo_sv + fo_ev*ed.y;
    av2 += b2f(v4.z)*fo_sv + fo_ev*ed.z;
}

// ---------------- fused filter + gather aggregation (R1 structure, proven; no swizzle) ----------------
// l0: layer-0 v-base computed from E_flat*vec_w (v0 array eliminated).
__global__ __launch_bounds__(256) __attribute__((amdgpu_waves_per_eu(4,8)))
void agg_kernel(
    const float* __restrict__ s_prev_f, int s_ldaf,
    const float* __restrict__ v_prev_f, int v_nstrf,
    const ushort4* __restrict__ sq, const ushort4* __restrict__ vq,
    const EdgeRec* __restrict__ erec_csr,
    const int* __restrict__ sd_csr, const int* __restrict__ row_off,
    const _Float16* __restrict__ wf, const float* __restrict__ fb,
    float* __restrict__ s_mid, float* __restrict__ v_mid,
    u16* __restrict__ vmid4_bf,
    const float* __restrict__ E_flat, const float* __restrict__ vec_w, int l0)
{
    const int f   = threadIdx.x & 127;
    const int sub = threadIdx.x >> 7;
    h16x2 wp[30];
    #pragma unroll
    for (int rsel=0; rsel<3; ++rsel){
        const h16x4* rp = (const h16x4*)(wf + (size_t)(rsel*FD + f)*KR);
        #pragma unroll
        for (int i=0;i<5;++i){
            union { h16x4 v; h16x2 p[2]; } t; t.v = rp[i];
            wp[rsel*10+2*i]   = t.p[0];
            wp[rsel*10+2*i+1] = t.p[1];
        }
    }
    const float b0 = fb[f], b1 = fb[FD+f], b2 = fb[2*FD+f];

    const int n = blockIdx.x*2 + sub;
    const int beg = __builtin_amdgcn_readfirstlane(row_off[n]);
    const int end = __builtin_amdgcn_readfirstlane(row_off[n+1]);
    float acc_s=0.f, av0=0.f, av1=0.f, av2=0.f;

    // prologue: load pair 0 (guarded via clamped indices; index 0 is a safe dummy)
    int i0 = (beg   < end) ? beg   : 0;
    int i1 = (beg+1 < end) ? beg+1 : i0;
    int sd0 = __builtin_amdgcn_readfirstlane(sd_csr[i0]);
    int sd1 = __builtin_amdgcn_readfirstlane(sd_csr[i1]);
    ushort4 sA = sq[(size_t)sd0*FD + f];
    ushort4 vA = vq[(size_t)sd0*FD + f];
    ushort4 sB = sq[(size_t)sd1*FD + f];
    ushort4 vB = vq[(size_t)sd1*FD + f];
    EdgeRec r0 = erec_csr[i0];
    EdgeRec r1 = erec_csr[i1];

    for (int idx = beg; idx + 2 <= end; idx += 2) {
        // prefetch next pair while this pair computes
        int j0 = (idx+2 < end) ? idx+2 : 0;
        int j1 = (idx+3 < end) ? idx+3 : j0;
        int nsd0 = __builtin_amdgcn_readfirstlane(sd_csr[j0]);
        int nsd1 = __builtin_amdgcn_readfirstlane(sd_csr[j1]);
        ushort4 nsA = sq[(size_t)nsd0*FD + f];
        ushort4 nvA = vq[(size_t)nsd0*FD + f];
        ushort4 nsB = sq[(size_t)nsd1*FD + f];
        ushort4 nvB = vq[(size_t)nsd1*FD + f];
        EdgeRec nr0 = erec_csr[j0];
        EdgeRec nr1 = erec_csr[j1];

        edge_step(r0, sA, vA, wp, b0,b1,b2, acc_s, av0, av1, av2);
        edge_step(r1, sB, vB, wp, b0,b1,b2, acc_s, av0, av1, av2);

        sA=nsA; vA=nvA; sB=nsB; vB=nvB; r0=nr0; r1=nr1;
    }
    // tail: when degree is odd, the last edge's data has rotated into slot A
    if (((end - beg) & 1) && beg < end) {
        edge_step(r0, sA, vA, wp, b0,b1,b2, acc_s, av0, av1, av2);
    }

    float smv = s_prev_f[(size_t)n*s_ldaf+f] + acc_s;
    s_mid[(size_t)n*FD+f] = smv;
    float base0, base1, base2;
    if (l0) {
        float e0 = E_flat[(size_t)n*3+0];
        float e1 = E_flat[(size_t)n*3+1];
        float e2 = E_flat[(size_t)n*3+2];
        float vw = vec_w[f];
        base0 = e0*vw; base1 = e1*vw; base2 = e2*vw;
    } else {
        const float* vp = v_prev_f + (size_t)n*v_nstrf;
        base0 = vp[f]; base1 = vp[FD+f]; base2 = vp[2*FD+f];
    }
    float o0 = base0+av0, o1 = base1+av1, o2 = base2+av2;
    size_t vo = (size_t)n*F3;
    v_mid[vo+f]=o0;        v_mid[vo+FD+f]=o1;        v_mid[vo+2*FD+f]=o2;
    size_t v4 = (size_t)n*512;                // node-padded bf16 (row 4n+3 stays 0)
    vmid4_bf[v4+f]=f2b(o0); vmid4_bf[v4+FD+f]=f2b(o1); vmid4_bf[v4+2*FD+f]=f2b(o2);
}

extern "C" void kernel_launch(void* const* d_in, const int* in_sizes, int n_in,
                              void* d_out, int out_size, void* d_ws, size_t ws_size,
                              hipStream_t stream)
{
    (void)in_sizes; (void)n_in; (void)out_size; (void)ws_size;
    const float* atom_xyz = (const float*)d_in[0];
    const float* cell     = (const float*)d_in[1];
    const int*   nodes    = (const int*)d_in[2];
    const int*   aedges   = (const int*)d_in[3];
    const float* edisp    = (const float*)d_in[4];
    const float* V_flat   = (const float*)d_in[5];
    const float* E_flat   = (const float*)d_in[6];
    const float* atom_emb = (const float*)d_in[7];
    const float* pot_W    = (const float*)d_in[8];
    const float* pot_b    = (const float*)d_in[9];
    const float* init_W1  = (const float*)d_in[10];
    const float* init_b1  = (const float*)d_in[11];
    const float* init_W2  = (const float*)d_in[12];
    const float* init_b2  = (const float*)d_in[13];
    const float* vec_w    = (const float*)d_in[14];
    const float* filt_W   = (const float*)d_in[15];
    const float* filt_b   = (const float*)d_in[16];
    const float* msg_W1   = (const float*)d_in[17];
    const float* msg_b1   = (const float*)d_in[18];
    const float* msg_W2   = (const float*)d_in[19];
    const float* msg_b2   = (const float*)d_in[20];
    const float* U_W      = (const float*)d_in[21];
    const float* V_W      = (const float*)d_in[22];
    const float* upd_W1   = (const float*)d_in[23];
    const float* upd_b1   = (const float*)d_in[24];
    const float* upd_W2   = (const float*)d_in[25];
    const float* upd_b2   = (const float*)d_in[26];

    float* out = (float*)d_out;
    char* base = (char*)d_ws;
    size_t o = 0;
    auto alloc = [&](size_t bytes)->char* { char* r = base + o; o += (bytes + 255) & ~(size_t)255; return r; };

    float* s0     = (float*)alloc((size_t)NTOT*FD*4);
    float* s_mid  = (float*)alloc((size_t)NTOT*FD*4);
    float* v_mid  = (float*)alloc((size_t)NTOT*F3*4);
    EdgeRec* erec_csr = (EdgeRec*)alloc((size_t)ETOT*sizeof(EdgeRec));
    u16* s_bf     = (u16*)alloc((size_t)NTOT*FD*2);
    u16* sq       = (u16*)alloc((size_t)NTOT*FD*4*2);   // quads {so0,so1,so2,s}
    u16* vq       = (u16*)alloc((size_t)NTOT*FD*4*2);   // quads {v0,v1,v2,pad}
    u16* vmid4_bf = (u16*)alloc((size_t)NTOT*4*FD*2);   // node-padded bf16 (row 4n+3 = 0)
    u16* wts      = (u16*)alloc((size_t)589824*2);
    _Float16* wf16 = (_Float16*)alloc((size_t)3*F3*KR*2);
    int* sd_csr   = (int*)alloc((size_t)ETOT*4);
    int* row_off  = (int*)alloc((size_t)(NTOT+1)*4);
    int* counts   = (int*)alloc((size_t)NTOT*4);
    int* cursor   = (int*)alloc((size_t)NTOT*4);

    hipMemsetAsync(counts, 0, NTOT*sizeof(int), stream);
    hipMemsetAsync(cursor, 0, NTOT*sizeof(int), stream);
    hipMemsetAsync(vmid4_bf, 0, (size_t)NTOT*4*FD*2, stream);  // pad rows stay 0 all layers

    ecount_kernel<<<ETOT/256, 256, 0, stream>>>(aedges, counts);
    scan_kernel<<<1, 1024, 0, stream>>>(counts, row_off);
    fill_kernel<<<ETOT/256, 256, 0, stream>>>(atom_xyz, cell, aedges, edisp,
        row_off, cursor, sd_csr, erec_csr);
    wconv_kernel<<<(589824+255)/256, 256, 0, stream>>>(
        init_W1, init_W2, msg_W1, msg_W2, U_W, V_W, upd_W1, upd_W2, wts);
    wfilt_kernel<<<(3*F3*KR+255)/256, 256, 0, stream>>>(filt_W, wf16);

    const u16* w_init1 = wts + 0;
    const u16* w_init2 = wts + 32768;
    const u16* w_msg1  = wts + 49152;    // 3 x 16384
    const u16* w_msg2  = wts + 98304;    // 3 x 49152
    const u16* w_UV    = wts + 245760;   // 3 x 32768: per layer [U rows | V rows]
    const u16* w_upd1  = wts + 344064;   // 3 x 32768
    const u16* w_upd2  = wts + 442368;   // 3 x 49152

    hinit_kernel<<<NTOT/16, 256, 0, stream>>>(
        nodes, atom_emb, V_flat, pot_W, pot_b,
        w_init1, init_b1, w_init2, init_b2, s0, s_bf, sq);
    v0_kernel<<<NTOT*F3/256, 256, 0, stream>>>(E_flat, vec_w, vq);

    const float* s_prev_f = s0;  int s_ldaf  = FD;
    const float* v_prev_f = s0;  int v_nstrf = 0;   // unused for l=0 (l0 flag)
    for (int l = 0; l < 3; ++l) {
        msgmlp_kernel<<<NTOT/16, 256, 0, stream>>>(
            s_bf, w_msg1 + (size_t)l*16384, msg_b1 + (size_t)l*FD,
            w_msg2 + (size_t)l*49152, msg_b2 + (size_t)l*F3, sq);
        agg_kernel<<<NTOT/2, 256, 0, stream>>>(s_prev_f, s_ldaf, v_prev_f, v_nstrf,
            (const ushort4*)sq, (const ushort4*)vq, erec_csr, sd_csr, row_off,
            wf16 + (size_t)l*F3*KR, filt_b + (size_t)l*F3, s_mid, v_mid, vmid4_bf,
            E_flat, vec_w, l == 0 ? 1 : 0);
        float* outp = out + (size_t)l*NTOT*512;
        upduv_kernel<<<NTOT/16, 256, 0, stream>>>(
            vmid4_bf, w_UV + (size_t)l*32768,
            w_upd1 + (size_t)l*32768, upd_b1 + (size_t)l*FD,
            w_upd2 + (size_t)l*49152, upd_b2 + (size_t)l*F3,
            s_mid, v_mid, outp, s_bf, sq, vq);
        s_prev_f = outp;        s_ldaf  = 512;
        v_prev_f = outp + FD;   v_nstrf = 512;
    }
}